// Round 12
// baseline (148.014 us; speedup 1.0000x reference)
//
#include <hip/hip_runtime.h>
#include <math.h>

#define TT 2048
#define CDIM 1024
#define BT 4096
#define NT16 16   // K tiles (K = 1024, BK = 64)

typedef __attribute__((ext_vector_type(8))) short bf16x8;
typedef __attribute__((ext_vector_type(4))) short short4v;
typedef __attribute__((ext_vector_type(4))) float f32x4;
typedef __attribute__((ext_vector_type(16))) float f32x16;

static __device__ __forceinline__ short f2bf(float f) {
  union { float f; unsigned int u; } c; c.f = f;
  unsigned int u = c.u;
  u += 0x7fff + ((u >> 16) & 1);   // round-to-nearest-even
  return (short)(u >> 16);
}

static __device__ __forceinline__ void gload_lds16(const void* g, void* l) {
  __builtin_amdgcn_global_load_lds(
      (const __attribute__((address_space(1))) void*)g,
      (__attribute__((address_space(3))) void*)l, 16, 0, 0);
}

static __device__ __forceinline__ unsigned int cvt_pk_bf16(float lo, float hi) {
  unsigned int r;
  asm("v_cvt_pk_bf16_f32 %0, %1, %2" : "=v"(r) : "v"(lo), "v"(hi));
  return r;
}

// ---------------------------------------------------------------------------
// packx: x fp32 -> bf16, flat. 8 elems/thread.
__global__ __launch_bounds__(256) void packx_kernel(
    const float* __restrict__ x, short* __restrict__ Xb) {
  const size_t i = ((size_t)blockIdx.x * 256 + threadIdx.x) * 8;
  float4 v0 = *(const float4*)(x + i);
  float4 v1 = *(const float4*)(x + i + 4);
  bf16x8 p;
  p[0] = f2bf(v0.x); p[1] = f2bf(v0.y); p[2] = f2bf(v0.z); p[3] = f2bf(v0.w);
  p[4] = f2bf(v1.x); p[5] = f2bf(v1.y); p[6] = f2bf(v1.z); p[7] = f2bf(v1.w);
  *(bf16x8*)(Xb + i) = p;
}

// ---------------------------------------------------------------------------
// packw_eff: Weff = W + 2*(B@A), fp32 accum, single bf16 rounding.
__global__ __launch_bounds__(256) void packw_eff_kernel(
    const float* __restrict__ W, const float* __restrict__ Bm,
    const float* __restrict__ Aa, short* __restrict__ Waug) {
  __shared__ float Als[16 * 1024];
  const int tid = threadIdx.x;
  for (int i = tid; i < 4096; i += 256)
    ((float4*)Als)[i] = ((const float4*)Aa)[i];
  __syncthreads();
  const int row = blockIdx.x * 2 + (tid >> 7);
  const int c8 = (tid & 127) * 8;
  float4 w0 = *(const float4*)(W + (size_t)row * 1024 + c8);
  float4 w1 = *(const float4*)(W + (size_t)row * 1024 + c8 + 4);
  float acc[8] = {w0.x, w0.y, w0.z, w0.w, w1.x, w1.y, w1.z, w1.w};
  const float* brow = Bm + (size_t)row * 16;
#pragma unroll
  for (int r = 0; r < 16; r++) {
    float b2 = 2.f * brow[r];
#pragma unroll
    for (int j = 0; j < 8; j++) acc[j] += b2 * Als[r * 1024 + c8 + j];
  }
  bf16x8 p;
#pragma unroll
  for (int j = 0; j < 8; j++) p[j] = f2bf(acc[j]);
  *(bf16x8*)(Waug + (size_t)row * 1024 + c8) = p;
}

// ---------------------------------------------------------------------------
// QKV GEMM: 128x128 tile, K=1024, 3-buffer ring with FULL-TILE prefetch
// distance (never-draining counted vmcnt). LDS 96KB = 3 bufs x {A 16KB,
// B 16KB}; 1 block/CU. Per tile t (data in buf t%3): issue STAGE(t+2) into
// buf (t+2)%3 FIRST, compute tile t, then vmcnt(8) (retires T(t+1)'s 8 loads
// — issued a FULL TILE ago, covers even HBM 900cy; leaves T(t+2)'s 8 in
// flight) + one barrier. Queue never drains mid-loop.
// Hazards: buf (t+2)%3 = buf (t-1)%3 whose reads finished before end-of-(t-1)
// barrier (lgkmcnt-gated MFMAs); buf t%3 readiness gated by prior vmcnt.
// Tails: t=13 stages T15, vmcnt(8); t=14 no stage, vmcnt(0); t=15 no-op.
// Grid 768 = 32m x 24n, L2-aware XCD map (XCD x owns 8m x 12n region).
__global__ __launch_bounds__(256) void gemm_qkv_kernel(
    const short* __restrict__ Amat, const short* __restrict__ Bmat,
    const float* __restrict__ bias,
    const float* __restrict__ kv_scale, const float* __restrict__ kv_zp,
    short* __restrict__ Qb, short* __restrict__ Kb, short* __restrict__ Vt) {
  __shared__ short lds[3 * 2 * 128 * 64];   // 96 KB
  char* const ldsB = (char*)lds;
  const int tid = threadIdx.x;
  const int lane = tid & 63;
  const int wid = tid >> 6;
  const int wr = wid >> 1, wc = wid & 1;
  const int r16 = lane & 15, g = lane >> 4;

  // L2-aware XCD mapping (grid 768 = 32m x 24n; XCD x gets 8m x 12n)
  const int x = blockIdx.x & 7;
  const int l = blockIdx.x >> 3;
  const int bm = ((x & 3) * 8 + (l & 7)) * 128;
  const int bn = (((x >> 2) * 12) + (l >> 3)) * 128;

  // stage one K-tile (A+B) into buffer `buf` (0/1/2); LDS chunk (row,cs)
  // holds global chunk (row, cs^(row&7)); dest byte = chunkIndex*16 (linear).
  // Buffer stride 32768 B: A at +0, B at +16384.
#define STAGE_TILE(buf, k0)                                                   \
  do {                                                                        \
    _Pragma("unroll") for (int i = 0; i < 4; i++) {                           \
      int L = i * 256 + tid;                                                  \
      int row = L >> 3;                                                       \
      int cg = (L & 7) ^ (row & 7);                                           \
      char* d = ldsB + (buf) * 32768 + (i * 256 + wid * 64) * 16;             \
      gload_lds16(Amat + (size_t)(bm + row) * CDIM + (k0) + cg * 8, d);       \
      gload_lds16(Bmat + (size_t)(bn + row) * CDIM + (k0) + cg * 8,           \
                  d + 16384);                                                 \
    }                                                                         \
  } while (0)

  f32x4 zero = {0.f, 0.f, 0.f, 0.f};
  f32x4 acc[4][4];
#pragma unroll
  for (int i = 0; i < 4; i++)
#pragma unroll
    for (int j = 0; j < 4; j++) acc[i][j] = zero;

  // prologue: stage T0 and T1; wait T0 only (T1 stays in flight)
  STAGE_TILE(0, 0);
  STAGE_TILE(1, 64);
  asm volatile("s_waitcnt vmcnt(8)" ::: "memory");
  __builtin_amdgcn_s_barrier();
  __builtin_amdgcn_sched_barrier(0);

  int cur = 0;   // t % 3
  for (int t = 0; t < NT16; ++t) {
    const int sb = (cur == 0) ? 2 : cur - 1;   // (t+2) % 3
    if (t + 2 < NT16) STAGE_TILE(sb, (t + 2) * 64);
    __builtin_amdgcn_sched_barrier(0);   // keep prefetch issue ahead of reads
    const char* Ab = ldsB + cur * 32768;
    const char* Bb = Ab + 16384;
#pragma unroll
    for (int kk = 0; kk < 2; kk++) {
      bf16x8 a[4], b[4];
#pragma unroll
      for (int mi = 0; mi < 4; mi++) {
        int row = wr * 64 + mi * 16 + r16;
        int cs = (kk * 4 + g) ^ (row & 7);
        a[mi] = *(const bf16x8*)(Ab + (row * 8 + cs) * 16);
      }
#pragma unroll
      for (int ni = 0; ni < 4; ni++) {
        int row = wc * 64 + ni * 16 + r16;
        int cs = (kk * 4 + g) ^ (row & 7);
        b[ni] = *(const bf16x8*)(Bb + (row * 8 + cs) * 16);
      }
      __builtin_amdgcn_s_setprio(1);
#pragma unroll
      for (int mi = 0; mi < 4; mi++)
#pragma unroll
        for (int ni = 0; ni < 4; ni++)
          acc[mi][ni] = __builtin_amdgcn_mfma_f32_16x16x32_bf16(
              a[mi], b[ni], acc[mi][ni], 0, 0, 0);
      __builtin_amdgcn_s_setprio(0);
    }
    // retire T(t+1) (issued one full tile ago); keep T(t+2) in flight
    if (t + 2 < NT16) {
      asm volatile("s_waitcnt vmcnt(8)" ::: "memory");
    } else {
      asm volatile("s_waitcnt vmcnt(0)" ::: "memory");
    }
    __builtin_amdgcn_s_barrier();
    __builtin_amdgcn_sched_barrier(0);
    cur = (cur == 2) ? 0 : cur + 1;
  }
#undef STAGE_TILE

  // epilogue (verified R4/R7): bias, Q scale, fake-quant K/V, V transposed
  const float scale = kv_scale[0];
  const float zp = kv_zp[0];
  const int which = bn >> 10;  // 0=Q 1=K 2=V (uniform per block)
#pragma unroll
  for (int mi = 0; mi < 4; mi++)
#pragma unroll
    for (int ni = 0; ni < 4; ni++)
#pragma unroll
      for (int r = 0; r < 4; r++) {
        int m = bm + wr * 64 + mi * 16 + g * 4 + r;
        int n = bn + wc * 64 + ni * 16 + r16;
        float val = acc[mi][ni][r] + bias[n];
        int hn = n & 1023;
        int bhm = (m >> 11) * 16 + (hn >> 6);
        int tq = m & 2047;
        int dd = hn & 63;
        if (which == 0) {
          Qb[((size_t)bhm * TT + tq) * 64 + dd] =
              f2bf(val * 0.125f * 1.44269504088896340736f);
        } else {
          float q = rintf(val / scale + zp);   // round-half-even like jnp.round
          q = fminf(fmaxf(q, 0.f), 255.f);
          float deq = (q - zp) * scale;
          if (which == 1) Kb[((size_t)bhm * TT + tq) * 64 + dd] = f2bf(deq);
          else            Vt[((size_t)bhm * 64 + dd) * TT + tq] = f2bf(deq);
        }
      }
}

// ---------------------------------------------------------------------------
// proj GEMM: 128x128, K=1024, 2-phase dbuf (verified R8/R9 structure).
__global__ __launch_bounds__(256) void gemm_proj_kernel(
    const short* __restrict__ Amat, const short* __restrict__ Bmat,
    const float* __restrict__ bias, float* __restrict__ Out) {
  __shared__ short lds[2 * 2 * 128 * 64];   // 64 KB
  char* const ldsB = (char*)lds;
  const int tid = threadIdx.x;
  const int lane = tid & 63;
  const int wid = tid >> 6;
  const int wr = wid >> 1, wc = wid & 1;
  const int r16 = lane & 15, g = lane >> 4;

  const int x = blockIdx.x & 7;
  const int l = blockIdx.x >> 3;
  const int bm = ((x & 3) * 8 + (l & 7)) * 128;
  const int bn = (((x >> 2) * 4) + (l >> 3)) * 128;

#define STAGE_TILE(buf, k0)                                                   \
  do {                                                                        \
    _Pragma("unroll") for (int i = 0; i < 4; i++) {                           \
      int L = i * 256 + tid;                                                  \
      int row = L >> 3;                                                       \
      int cg = (L & 7) ^ (row & 7);                                           \
      char* d = ldsB + (buf) * 32768 + (i * 256 + wid * 64) * 16;             \
      gload_lds16(Amat + (size_t)(bm + row) * CDIM + (k0) + cg * 8, d);       \
      gload_lds16(Bmat + (size_t)(bn + row) * CDIM + (k0) + cg * 8,           \
                  d + 16384);                                                 \
    }                                                                         \
  } while (0)

  f32x4 zero = {0.f, 0.f, 0.f, 0.f};
  f32x4 acc[4][4];
#pragma unroll
  for (int i = 0; i < 4; i++)
#pragma unroll
    for (int j = 0; j < 4; j++) acc[i][j] = zero;

  STAGE_TILE(0, 0);
  asm volatile("s_waitcnt vmcnt(0)" ::: "memory");
  __builtin_amdgcn_s_barrier();
  __builtin_amdgcn_sched_barrier(0);

  int cur = 0;
  for (int t = 0; t < NT16; ++t) {
    if (t + 1 < NT16) STAGE_TILE(cur ^ 1, (t + 1) * 64);
    __builtin_amdgcn_sched_barrier(0);
    const char* Ab = ldsB + cur * 32768;
    const char* Bb = Ab + 16384;
#pragma unroll
    for (int kk = 0; kk < 2; kk++) {
      bf16x8 a[4], b[4];
#pragma unroll
      for (int mi = 0; mi < 4; mi++) {
        int row = wr * 64 + mi * 16 + r16;
        int cs = (kk * 4 + g) ^ (row & 7);
        a[mi] = *(const bf16x8*)(Ab + (row * 8 + cs) * 16);
      }
#pragma unroll
      for (int ni = 0; ni < 4; ni++) {
        int row = wc * 64 + ni * 16 + r16;
        int cs = (kk * 4 + g) ^ (row & 7);
        b[ni] = *(const bf16x8*)(Bb + (row * 8 + cs) * 16);
      }
      __builtin_amdgcn_s_setprio(1);
#pragma unroll
      for (int mi = 0; mi < 4; mi++)
#pragma unroll
        for (int ni = 0; ni < 4; ni++)
          acc[mi][ni] = __builtin_amdgcn_mfma_f32_16x16x32_bf16(
              a[mi], b[ni], acc[mi][ni], 0, 0, 0);
      __builtin_amdgcn_s_setprio(0);
    }
    asm volatile("s_waitcnt vmcnt(0)" ::: "memory");
    __builtin_amdgcn_s_barrier();
    __builtin_amdgcn_sched_barrier(0);
    cur ^= 1;
  }
#undef STAGE_TILE

#pragma unroll
  for (int mi = 0; mi < 4; mi++)
#pragma unroll
    for (int ni = 0; ni < 4; ni++)
#pragma unroll
      for (int r = 0; r < 4; r++) {
        int m = bm + wr * 64 + mi * 16 + g * 4 + r;
        int n = bn + wc * 64 + ni * 16 + r16;
        Out[(size_t)m * CDIM + n] = acc[mi][ni][r] + bias[n];
      }
}

// ---------------------------------------------------------------------------
// Causal flash attention (verified R7/R8 structure) — ctx to Cb, stride CDIM.
__global__ __launch_bounds__(512) void attn_kernel(
    const short* __restrict__ Qb, const short* __restrict__ Kb,
    const short* __restrict__ Vt, short* __restrict__ Cb) {
  __shared__ short Kls[4 * 4096];
  __shared__ short Vls[4 * 4096];
  const int tid = threadIdx.x;
  const int lane = tid & 63;
  const int w = tid >> 6;
  const int qsub = w & 3;
  const int p = w >> 2;
  const int q32 = lane & 31;
  const int hi = lane >> 5;
  const int xid = blockIdx.x & 7;
  const int lix = blockIdx.x >> 3;
  const int bh = xid * 4 + (lix & 3);
  const int bx = lix >> 2;
  const size_t kvbase = (size_t)bh * TT * 64;
  const int swz = q32 & 7;
  const int b = bh >> 4, h = bh & 15;

  const int srow = tid >> 3;
  const int scg = (tid & 7) ^ (srow & 7);
  const int sdst = w * 1024;

  for (int seg = 0; seg < 2; seg++) {
    const int qb = seg ? bx : 15 - bx;
    const int q0 = qb * 128;
    const int q0w = q0 + qsub * 32;
    const int ns = qb + 1;

    bf16x8 qf[4];
    {
      const short* qp = Qb + kvbase + (size_t)(q0w + q32) * 64;
#pragma unroll
      for (int kd = 0; kd < 4; kd++)
        qf[kd] = *(const bf16x8*)(qp + kd * 16 + hi * 8);
    }
    f32x16 accT[2];
#pragma unroll
    for (int i = 0; i < 16; i++) { accT[0][i] = 0.f; accT[1][i] = 0.f; }
    float m_run = -1e30f, l_run = 0.f;

#pragma unroll
    for (int t2 = 0; t2 < 2; t2++) {
      int kv0 = t2 * 64;
      gload_lds16(Kb + kvbase + (size_t)(kv0 + srow) * 64 + scg * 8,
                  (char*)Kls + t2 * 8192 + sdst);
      gload_lds16(Vt + kvbase + (size_t)srow * TT + kv0 + scg * 8,
                  (char*)Vls + t2 * 8192 + sdst);
    }
    asm volatile("s_waitcnt vmcnt(0)" ::: "memory");
    __builtin_amdgcn_s_barrier();
    __builtin_amdgcn_sched_barrier(0);

    for (int s = 0; s < ns; s++) {
      if (s + 1 < ns) {
        const int bp = ((s + 1) & 1) * 2;
#pragma unroll
        for (int t2 = 0; t2 < 2; t2++) {
          int kv0 = (2 * (s + 1) + t2) * 64;
          gload_lds16(Kb + kvbase + (size_t)(kv0 + srow) * 64 + scg * 8,
                      (char*)Kls + (bp + t2) * 8192 + sdst);
          gload_lds16(Vt + kvbase + (size_t)srow * TT + kv0 + scg * 8,
                      (char*)Vls + (bp + t2) * 8192 + sdst);
        }
      }
      const int kv0 = (2 * s + p) * 64;
      if (kv0 <= q0w + 31) {
        const char* Kbase = (const char*)Kls + (2 * (s & 1) + p) * 8192;
        const char* Vbase = (const char*)Vls + (2 * (s & 1) + p) * 8192;
        f32x16 sA, sB;
#pragma unroll
        for (int i = 0; i < 16; i++) { sA[i] = 0.f; sB[i] = 0.f; }
        __builtin_amdgcn_s_setprio(1);
#pragma unroll
        for (int kd = 0; kd < 4; kd++) {
          int coff = ((kd * 2 + hi) ^ swz) * 16;
          bf16x8 a0 = *(const bf16x8*)(Kbase + q32 * 128 + coff);
          bf16x8 a1 = *(const bf16x8*)(Kbase + (32 + q32) * 128 + coff);
          sA = __builtin_amdgcn_mfma_f32_32x32x16_bf16(a0, qf[kd], sA, 0, 0, 0);
          sB = __builtin_amdgcn_mfma_f32_32x32x16_bf16(a1, qf[kd], sB, 0, 0, 0);
        }
        __builtin_amdgcn_s_setprio(0);
        const int qg = q0w + q32;
        if (kv0 + 63 > q0w) {
#pragma unroll
          for (int r = 0; r < 16; r++) {
            int kvr = kv0 + (r & 3) + 8 * (r >> 2) + 4 * hi;
            if (kvr > qg) sA[r] = -1e30f;
            if (kvr + 32 > qg) sB[r] = -1e30f;
          }
        }
        float mx = sA[0];
#pragma unroll
        for (int r = 1; r < 16; r++) mx = fmaxf(mx, sA[r]);
#pragma unroll
        for (int r = 0; r < 16; r++) mx = fmaxf(mx, sB[r]);
        mx = fmaxf(mx, __shfl_xor(mx, 32));
        float mnew = fmaxf(m_run, mx);
        float corr = exp2f(m_run - mnew);
        float rs = 0.f;
#pragma unroll
        for (int r = 0; r < 16; r++) {
          sA[r] = exp2f(sA[r] - mnew);
          sB[r] = exp2f(sB[r] - mnew);
          rs += sA[r] + sB[r];
        }
        rs += __shfl_xor(rs, 32);
        l_run = l_run * corr + rs;
        m_run = mnew;
#pragma unroll
        for (int r = 0; r < 16; r++) { accT[0][r] *= corr; accT[1][r] *= corr; }

        bf16x8 pf[4];
#pragma unroll
        for (int t2 = 0; t2 < 2; t2++) {
#pragma unroll
          for (int s01 = 0; s01 < 2; s01++) {
            int base = 8 * s01;
            unsigned int wlo0, wlo1, whi0, whi1;
            if (t2 == 0) {
              wlo0 = cvt_pk_bf16(sA[base + 0], sA[base + 1]);
              wlo1 = cvt_pk_bf16(sA[base + 2], sA[base + 3]);
              whi0 = cvt_pk_bf16(sA[base + 4], sA[base + 5]);
              whi1 = cvt_pk_bf16(sA[base + 6], sA[base + 7]);
            } else {
              wlo0 = cvt_pk_bf16(sB[base + 0], sB[base + 1]);
              wlo1 = cvt_pk_bf16(sB[base + 2], sB[base + 3]);
              whi0 = cvt_pk_bf16(sB[base + 4], sB[base + 5]);
              whi1 = cvt_pk_bf16(sB[base + 6], sB[base + 7]);
            }
            asm volatile("v_permlane32_swap_b32 %0, %1" : "+v"(wlo0), "+v"(whi0));
            asm volatile("v_permlane32_swap_b32 %0, %1" : "+v"(wlo1), "+v"(whi1));
            union { unsigned int u[4]; bf16x8 v; } cc;
            cc.u[0] = wlo0; cc.u[1] = wlo1; cc.u[2] = whi0; cc.u[3] = whi1;
            pf[t2 * 2 + s01] = cc.v;
          }
        }
        __builtin_amdgcn_s_setprio(1);
#pragma unroll
        for (int db = 0; db < 2; db++) {
          const int row = db * 32 + q32;
#pragma unroll
          for (int ks = 0; ks < 4; ks++) {
            bf16x8 vf = *(const bf16x8*)(Vbase + row * 128 +
                                         (((ks * 2 + hi) ^ swz) * 16));
            accT[db] = __builtin_amdgcn_mfma_f32_32x32x16_bf16(vf, pf[ks],
                                                               accT[db], 0, 0, 0);
          }
        }
        __builtin_amdgcn_s_setprio(0);
      }
      asm volatile("s_waitcnt vmcnt(0) lgkmcnt(0)" ::: "memory");
      __builtin_amdgcn_s_barrier();
      __builtin_amdgcn_sched_barrier(0);
    }

    float* scrO = (float*)Kls;
    float* scrML = (float*)Vls;
    if (p == 1) {
#pragma unroll
      for (int db = 0; db < 2; db++)
#pragma unroll
        for (int r = 0; r < 16; r++)
          scrO[qsub * 2048 + (db * 16 + r) * 64 + lane] = accT[db][r];
      scrML[qsub * 64 + lane] = m_run;
      scrML[256 + qsub * 64 + lane] = l_run;
    }
    __syncthreads();
    if (p == 0) {
      float m_o = scrML[qsub * 64 + lane];
      float l_o = scrML[256 + qsub * 64 + lane];
      float mm = fmaxf(m_run, m_o);
      float ce = exp2f(m_run - mm), co = exp2f(m_o - mm);
      float lt = l_run * ce + l_o * co;
      float rinv = 1.f / lt;
      short* cp = Cb + (size_t)(b * TT + q0w + q32) * CDIM + h * 64;
#pragma unroll
      for (int db = 0; db < 2; db++)
#pragma unroll
        for (int rg = 0; rg < 4; rg++) {
          short4v pk4;
#pragma unroll
          for (int rr = 0; rr < 4; rr++) {
            int r = rg * 4 + rr;
            float v = accT[db][r] * ce +
                      scrO[qsub * 2048 + (db * 16 + r) * 64 + lane] * co;
            pk4[rr] = f2bf(v * rinv);
          }
          *(short4v*)(cp + db * 32 + rg * 8 + hi * 4) = pk4;
        }
    }
    __syncthreads();
  }
}

// ---------------------------------------------------------------------------
extern "C" void kernel_launch(void* const* d_in, const int* in_sizes, int n_in,
                              void* d_out, int out_size, void* d_ws, size_t ws_size,
                              hipStream_t stream) {
  const float* x       = (const float*)d_in[0];
  const float* W_attn  = (const float*)d_in[1];
  const float* b_attn  = (const float*)d_in[2];
  const float* A_attn  = (const float*)d_in[3];
  const float* B_attn  = (const float*)d_in[4];
  const float* W_proj  = (const float*)d_in[5];
  const float* b_proj  = (const float*)d_in[6];
  const float* A_proj  = (const float*)d_in[7];
  const float* B_proj  = (const float*)d_in[8];
  const float* kv_scale = (const float*)d_in[9];
  const float* kv_zp    = (const float*)d_in[10];
  float* out = (float*)d_out;

  char* p = (char*)d_ws;
  short* Xb    = (short*)p; p += (size_t)BT * CDIM * 2;
  short* Waug1 = (short*)p; p += (size_t)3072 * CDIM * 2;
  short* Waug2 = (short*)p; p += (size_t)1024 * CDIM * 2;
  short* Cb    = (short*)p; p += (size_t)BT * CDIM * 2;
  short* Qb    = (short*)p; p += (size_t)32 * TT * 64 * 2;
  short* Kb    = (short*)p; p += (size_t)32 * TT * 64 * 2;
  short* Vt    = (short*)p; p += (size_t)32 * TT * 64 * 2;

  packx_kernel<<<dim3(2048), dim3(256), 0, stream>>>(x, Xb);
  packw_eff_kernel<<<dim3(1536), dim3(256), 0, stream>>>(
      W_attn, B_attn, A_attn, Waug1);
  packw_eff_kernel<<<dim3(512), dim3(256), 0, stream>>>(
      W_proj, B_proj, A_proj, Waug2);
  gemm_qkv_kernel<<<dim3(768), dim3(256), 0, stream>>>(
      Xb, Waug1, b_attn, kv_scale, kv_zp, Qb, Kb, Vt);
  attn_kernel<<<dim3(256), dim3(512), 0, stream>>>(Qb, Kb, Vt, Cb);
  gemm_proj_kernel<<<dim3(256), dim3(256), 0, stream>>>(
      Cb, Waug2, b_proj, out);
}

// Round 13
// 131.856 us; speedup vs baseline: 1.1225x; 1.1225x over previous
//
#include <hip/hip_runtime.h>
#include <math.h>

#define TT 2048
#define CDIM 1024
#define BT 4096
#define NT16 16   // K tiles (K = 1024, BK = 64)

typedef __attribute__((ext_vector_type(8))) short bf16x8;
typedef __attribute__((ext_vector_type(4))) short short4v;
typedef __attribute__((ext_vector_type(4))) float f32x4;
typedef __attribute__((ext_vector_type(16))) float f32x16;

static __device__ __forceinline__ short f2bf(float f) {
  union { float f; unsigned int u; } c; c.f = f;
  unsigned int u = c.u;
  u += 0x7fff + ((u >> 16) & 1);   // round-to-nearest-even
  return (short)(u >> 16);
}

static __device__ __forceinline__ void gload_lds16(const void* g, void* l) {
  __builtin_amdgcn_global_load_lds(
      (const __attribute__((address_space(1))) void*)g,
      (__attribute__((address_space(3))) void*)l, 16, 0, 0);
}

static __device__ __forceinline__ unsigned int cvt_pk_bf16(float lo, float hi) {
  unsigned int r;
  asm("v_cvt_pk_bf16_f32 %0, %1, %2" : "=v"(r) : "v"(lo), "v"(hi));
  return r;
}

// ---------------------------------------------------------------------------
// packx: x fp32 -> bf16, flat. 8 elems/thread.
__global__ __launch_bounds__(256) void packx_kernel(
    const float* __restrict__ x, short* __restrict__ Xb) {
  const size_t i = ((size_t)blockIdx.x * 256 + threadIdx.x) * 8;
  float4 v0 = *(const float4*)(x + i);
  float4 v1 = *(const float4*)(x + i + 4);
  bf16x8 p;
  p[0] = f2bf(v0.x); p[1] = f2bf(v0.y); p[2] = f2bf(v0.z); p[3] = f2bf(v0.w);
  p[4] = f2bf(v1.x); p[5] = f2bf(v1.y); p[6] = f2bf(v1.z); p[7] = f2bf(v1.w);
  *(bf16x8*)(Xb + i) = p;
}

// ---------------------------------------------------------------------------
// packw_eff: Weff = W + 2*(B@A), fp32 accum, single bf16 rounding.
__global__ __launch_bounds__(256) void packw_eff_kernel(
    const float* __restrict__ W, const float* __restrict__ Bm,
    const float* __restrict__ Aa, short* __restrict__ Waug) {
  __shared__ float Als[16 * 1024];
  const int tid = threadIdx.x;
  for (int i = tid; i < 4096; i += 256)
    ((float4*)Als)[i] = ((const float4*)Aa)[i];
  __syncthreads();
  const int row = blockIdx.x * 2 + (tid >> 7);
  const int c8 = (tid & 127) * 8;
  float4 w0 = *(const float4*)(W + (size_t)row * 1024 + c8);
  float4 w1 = *(const float4*)(W + (size_t)row * 1024 + c8 + 4);
  float acc[8] = {w0.x, w0.y, w0.z, w0.w, w1.x, w1.y, w1.z, w1.w};
  const float* brow = Bm + (size_t)row * 16;
#pragma unroll
  for (int r = 0; r < 16; r++) {
    float b2 = 2.f * brow[r];
#pragma unroll
    for (int j = 0; j < 8; j++) acc[j] += b2 * Als[r * 1024 + c8 + j];
  }
  bf16x8 p;
#pragma unroll
  for (int j = 0; j < 8; j++) p[j] = f2bf(acc[j]);
  *(bf16x8*)(Waug + (size_t)row * 1024 + c8) = p;
}

// ---------------------------------------------------------------------------
// QKV GEMM: 128x128 tile, K=1024, whole-tile 2-phase dbuf — the BEST measured
// structure across 7 schedule variants (R11: 82-86us). Per tile: issue
// STAGE(t+1) into buf^1 FIRST, then ds_read+MFMA on buf[cur], then ONE
// vmcnt(0)+barrier at tile end (wait distance = full tile compute; 2 blocks/CU
// co-resident at 64KB LDS absorb the residual stall).
// Grid 768 = 32m x 24n, L2-aware XCD map (XCD x owns 8m x 12n region).
__global__ __launch_bounds__(256) void gemm_qkv_kernel(
    const short* __restrict__ Amat, const short* __restrict__ Bmat,
    const float* __restrict__ bias,
    const float* __restrict__ kv_scale, const float* __restrict__ kv_zp,
    short* __restrict__ Qb, short* __restrict__ Kb, short* __restrict__ Vt) {
  __shared__ short lds[2 * 2 * 128 * 64];   // 64 KB
  char* const ldsB = (char*)lds;
  const int tid = threadIdx.x;
  const int lane = tid & 63;
  const int wid = tid >> 6;
  const int wr = wid >> 1, wc = wid & 1;
  const int r16 = lane & 15, g = lane >> 4;

  // L2-aware XCD mapping (grid 768 = 32m x 24n; XCD x gets 8m x 12n)
  const int x = blockIdx.x & 7;
  const int l = blockIdx.x >> 3;
  const int bm = ((x & 3) * 8 + (l & 7)) * 128;
  const int bn = (((x >> 2) * 12) + (l >> 3)) * 128;

  // stage one K-tile (A+B) into buffer `buf`; LDS chunk (row,cs) holds
  // global chunk (row, cs^(row&7)); dest byte = chunkIndex*16 (linear).
  // Buffer stride 32768 B: A at +0, B at +16384.
#define STAGE_TILE(buf, k0)                                                   \
  do {                                                                        \
    _Pragma("unroll") for (int i = 0; i < 4; i++) {                           \
      int L = i * 256 + tid;                                                  \
      int row = L >> 3;                                                       \
      int cg = (L & 7) ^ (row & 7);                                           \
      char* d = ldsB + (buf) * 32768 + (i * 256 + wid * 64) * 16;             \
      gload_lds16(Amat + (size_t)(bm + row) * CDIM + (k0) + cg * 8, d);       \
      gload_lds16(Bmat + (size_t)(bn + row) * CDIM + (k0) + cg * 8,           \
                  d + 16384);                                                 \
    }                                                                         \
  } while (0)

  f32x4 zero = {0.f, 0.f, 0.f, 0.f};
  f32x4 acc[4][4];
#pragma unroll
  for (int i = 0; i < 4; i++)
#pragma unroll
    for (int j = 0; j < 4; j++) acc[i][j] = zero;

  STAGE_TILE(0, 0);
  asm volatile("s_waitcnt vmcnt(0)" ::: "memory");
  __builtin_amdgcn_s_barrier();
  __builtin_amdgcn_sched_barrier(0);

  int cur = 0;
  for (int t = 0; t < NT16; ++t) {
    if (t + 1 < NT16) STAGE_TILE(cur ^ 1, (t + 1) * 64);
    __builtin_amdgcn_sched_barrier(0);   // keep prefetch issue ahead of reads
    const char* Ab = ldsB + cur * 32768;
    const char* Bb = Ab + 16384;
#pragma unroll
    for (int kk = 0; kk < 2; kk++) {
      bf16x8 a[4], b[4];
#pragma unroll
      for (int mi = 0; mi < 4; mi++) {
        int row = wr * 64 + mi * 16 + r16;
        int cs = (kk * 4 + g) ^ (row & 7);
        a[mi] = *(const bf16x8*)(Ab + (row * 8 + cs) * 16);
      }
#pragma unroll
      for (int ni = 0; ni < 4; ni++) {
        int row = wc * 64 + ni * 16 + r16;
        int cs = (kk * 4 + g) ^ (row & 7);
        b[ni] = *(const bf16x8*)(Bb + (row * 8 + cs) * 16);
      }
      __builtin_amdgcn_s_setprio(1);
#pragma unroll
      for (int mi = 0; mi < 4; mi++)
#pragma unroll
        for (int ni = 0; ni < 4; ni++)
          acc[mi][ni] = __builtin_amdgcn_mfma_f32_16x16x32_bf16(
              a[mi], b[ni], acc[mi][ni], 0, 0, 0);
      __builtin_amdgcn_s_setprio(0);
    }
    asm volatile("s_waitcnt vmcnt(0)" ::: "memory");
    __builtin_amdgcn_s_barrier();
    __builtin_amdgcn_sched_barrier(0);
    cur ^= 1;
  }
#undef STAGE_TILE

  // epilogue (verified R4/R7): bias, Q scale, fake-quant K/V, V transposed
  const float scale = kv_scale[0];
  const float zp = kv_zp[0];
  const int which = bn >> 10;  // 0=Q 1=K 2=V (uniform per block)
#pragma unroll
  for (int mi = 0; mi < 4; mi++)
#pragma unroll
    for (int ni = 0; ni < 4; ni++)
#pragma unroll
      for (int r = 0; r < 4; r++) {
        int m = bm + wr * 64 + mi * 16 + g * 4 + r;
        int n = bn + wc * 64 + ni * 16 + r16;
        float val = acc[mi][ni][r] + bias[n];
        int hn = n & 1023;
        int bhm = (m >> 11) * 16 + (hn >> 6);
        int tq = m & 2047;
        int dd = hn & 63;
        if (which == 0) {
          Qb[((size_t)bhm * TT + tq) * 64 + dd] =
              f2bf(val * 0.125f * 1.44269504088896340736f);
        } else {
          float q = rintf(val / scale + zp);   // round-half-even like jnp.round
          q = fminf(fmaxf(q, 0.f), 255.f);
          float deq = (q - zp) * scale;
          if (which == 1) Kb[((size_t)bhm * TT + tq) * 64 + dd] = f2bf(deq);
          else            Vt[((size_t)bhm * 64 + dd) * TT + tq] = f2bf(deq);
        }
      }
}

// ---------------------------------------------------------------------------
// proj GEMM: 128x128, K=1024, 2-phase dbuf (verified R8/R9 structure).
__global__ __launch_bounds__(256) void gemm_proj_kernel(
    const short* __restrict__ Amat, const short* __restrict__ Bmat,
    const float* __restrict__ bias, float* __restrict__ Out) {
  __shared__ short lds[2 * 2 * 128 * 64];   // 64 KB
  char* const ldsB = (char*)lds;
  const int tid = threadIdx.x;
  const int lane = tid & 63;
  const int wid = tid >> 6;
  const int wr = wid >> 1, wc = wid & 1;
  const int r16 = lane & 15, g = lane >> 4;

  const int x = blockIdx.x & 7;
  const int l = blockIdx.x >> 3;
  const int bm = ((x & 3) * 8 + (l & 7)) * 128;
  const int bn = (((x >> 2) * 4) + (l >> 3)) * 128;

#define STAGE_TILE(buf, k0)                                                   \
  do {                                                                        \
    _Pragma("unroll") for (int i = 0; i < 4; i++) {                           \
      int L = i * 256 + tid;                                                  \
      int row = L >> 3;                                                       \
      int cg = (L & 7) ^ (row & 7);                                           \
      char* d = ldsB + (buf) * 32768 + (i * 256 + wid * 64) * 16;             \
      gload_lds16(Amat + (size_t)(bm + row) * CDIM + (k0) + cg * 8, d);       \
      gload_lds16(Bmat + (size_t)(bn + row) * CDIM + (k0) + cg * 8,           \
                  d + 16384);                                                 \
    }                                                                         \
  } while (0)

  f32x4 zero = {0.f, 0.f, 0.f, 0.f};
  f32x4 acc[4][4];
#pragma unroll
  for (int i = 0; i < 4; i++)
#pragma unroll
    for (int j = 0; j < 4; j++) acc[i][j] = zero;

  STAGE_TILE(0, 0);
  asm volatile("s_waitcnt vmcnt(0)" ::: "memory");
  __builtin_amdgcn_s_barrier();
  __builtin_amdgcn_sched_barrier(0);

  int cur = 0;
  for (int t = 0; t < NT16; ++t) {
    if (t + 1 < NT16) STAGE_TILE(cur ^ 1, (t + 1) * 64);
    __builtin_amdgcn_sched_barrier(0);
    const char* Ab = ldsB + cur * 32768;
    const char* Bb = Ab + 16384;
#pragma unroll
    for (int kk = 0; kk < 2; kk++) {
      bf16x8 a[4], b[4];
#pragma unroll
      for (int mi = 0; mi < 4; mi++) {
        int row = wr * 64 + mi * 16 + r16;
        int cs = (kk * 4 + g) ^ (row & 7);
        a[mi] = *(const bf16x8*)(Ab + (row * 8 + cs) * 16);
      }
#pragma unroll
      for (int ni = 0; ni < 4; ni++) {
        int row = wc * 64 + ni * 16 + r16;
        int cs = (kk * 4 + g) ^ (row & 7);
        b[ni] = *(const bf16x8*)(Bb + (row * 8 + cs) * 16);
      }
      __builtin_amdgcn_s_setprio(1);
#pragma unroll
      for (int mi = 0; mi < 4; mi++)
#pragma unroll
        for (int ni = 0; ni < 4; ni++)
          acc[mi][ni] = __builtin_amdgcn_mfma_f32_16x16x32_bf16(
              a[mi], b[ni], acc[mi][ni], 0, 0, 0);
      __builtin_amdgcn_s_setprio(0);
    }
    asm volatile("s_waitcnt vmcnt(0)" ::: "memory");
    __builtin_amdgcn_s_barrier();
    __builtin_amdgcn_sched_barrier(0);
    cur ^= 1;
  }
#undef STAGE_TILE

#pragma unroll
  for (int mi = 0; mi < 4; mi++)
#pragma unroll
    for (int ni = 0; ni < 4; ni++)
#pragma unroll
      for (int r = 0; r < 4; r++) {
        int m = bm + wr * 64 + mi * 16 + g * 4 + r;
        int n = bn + wc * 64 + ni * 16 + r16;
        Out[(size_t)m * CDIM + n] = acc[mi][ni][r] + bias[n];
      }
}

// ---------------------------------------------------------------------------
// Causal flash attention (verified R7/R8 structure) — ctx to Cb, stride CDIM.
__global__ __launch_bounds__(512) void attn_kernel(
    const short* __restrict__ Qb, const short* __restrict__ Kb,
    const short* __restrict__ Vt, short* __restrict__ Cb) {
  __shared__ short Kls[4 * 4096];
  __shared__ short Vls[4 * 4096];
  const int tid = threadIdx.x;
  const int lane = tid & 63;
  const int w = tid >> 6;
  const int qsub = w & 3;
  const int p = w >> 2;
  const int q32 = lane & 31;
  const int hi = lane >> 5;
  const int xid = blockIdx.x & 7;
  const int lix = blockIdx.x >> 3;
  const int bh = xid * 4 + (lix & 3);
  const int bx = lix >> 2;
  const size_t kvbase = (size_t)bh * TT * 64;
  const int swz = q32 & 7;
  const int b = bh >> 4, h = bh & 15;

  const int srow = tid >> 3;
  const int scg = (tid & 7) ^ (srow & 7);
  const int sdst = w * 1024;

  for (int seg = 0; seg < 2; seg++) {
    const int qb = seg ? bx : 15 - bx;
    const int q0 = qb * 128;
    const int q0w = q0 + qsub * 32;
    const int ns = qb + 1;

    bf16x8 qf[4];
    {
      const short* qp = Qb + kvbase + (size_t)(q0w + q32) * 64;
#pragma unroll
      for (int kd = 0; kd < 4; kd++)
        qf[kd] = *(const bf16x8*)(qp + kd * 16 + hi * 8);
    }
    f32x16 accT[2];
#pragma unroll
    for (int i = 0; i < 16; i++) { accT[0][i] = 0.f; accT[1][i] = 0.f; }
    float m_run = -1e30f, l_run = 0.f;

#pragma unroll
    for (int t2 = 0; t2 < 2; t2++) {
      int kv0 = t2 * 64;
      gload_lds16(Kb + kvbase + (size_t)(kv0 + srow) * 64 + scg * 8,
                  (char*)Kls + t2 * 8192 + sdst);
      gload_lds16(Vt + kvbase + (size_t)srow * TT + kv0 + scg * 8,
                  (char*)Vls + t2 * 8192 + sdst);
    }
    asm volatile("s_waitcnt vmcnt(0)" ::: "memory");
    __builtin_amdgcn_s_barrier();
    __builtin_amdgcn_sched_barrier(0);

    for (int s = 0; s < ns; s++) {
      if (s + 1 < ns) {
        const int bp = ((s + 1) & 1) * 2;
#pragma unroll
        for (int t2 = 0; t2 < 2; t2++) {
          int kv0 = (2 * (s + 1) + t2) * 64;
          gload_lds16(Kb + kvbase + (size_t)(kv0 + srow) * 64 + scg * 8,
                      (char*)Kls + (bp + t2) * 8192 + sdst);
          gload_lds16(Vt + kvbase + (size_t)srow * TT + kv0 + scg * 8,
                      (char*)Vls + (bp + t2) * 8192 + sdst);
        }
      }
      const int kv0 = (2 * s + p) * 64;
      if (kv0 <= q0w + 31) {
        const char* Kbase = (const char*)Kls + (2 * (s & 1) + p) * 8192;
        const char* Vbase = (const char*)Vls + (2 * (s & 1) + p) * 8192;
        f32x16 sA, sB;
#pragma unroll
        for (int i = 0; i < 16; i++) { sA[i] = 0.f; sB[i] = 0.f; }
        __builtin_amdgcn_s_setprio(1);
#pragma unroll
        for (int kd = 0; kd < 4; kd++) {
          int coff = ((kd * 2 + hi) ^ swz) * 16;
          bf16x8 a0 = *(const bf16x8*)(Kbase + q32 * 128 + coff);
          bf16x8 a1 = *(const bf16x8*)(Kbase + (32 + q32) * 128 + coff);
          sA = __builtin_amdgcn_mfma_f32_32x32x16_bf16(a0, qf[kd], sA, 0, 0, 0);
          sB = __builtin_amdgcn_mfma_f32_32x32x16_bf16(a1, qf[kd], sB, 0, 0, 0);
        }
        __builtin_amdgcn_s_setprio(0);
        const int qg = q0w + q32;
        if (kv0 + 63 > q0w) {
#pragma unroll
          for (int r = 0; r < 16; r++) {
            int kvr = kv0 + (r & 3) + 8 * (r >> 2) + 4 * hi;
            if (kvr > qg) sA[r] = -1e30f;
            if (kvr + 32 > qg) sB[r] = -1e30f;
          }
        }
        float mx = sA[0];
#pragma unroll
        for (int r = 1; r < 16; r++) mx = fmaxf(mx, sA[r]);
#pragma unroll
        for (int r = 0; r < 16; r++) mx = fmaxf(mx, sB[r]);
        mx = fmaxf(mx, __shfl_xor(mx, 32));
        float mnew = fmaxf(m_run, mx);
        float corr = exp2f(m_run - mnew);
        float rs = 0.f;
#pragma unroll
        for (int r = 0; r < 16; r++) {
          sA[r] = exp2f(sA[r] - mnew);
          sB[r] = exp2f(sB[r] - mnew);
          rs += sA[r] + sB[r];
        }
        rs += __shfl_xor(rs, 32);
        l_run = l_run * corr + rs;
        m_run = mnew;
#pragma unroll
        for (int r = 0; r < 16; r++) { accT[0][r] *= corr; accT[1][r] *= corr; }

        bf16x8 pf[4];
#pragma unroll
        for (int t2 = 0; t2 < 2; t2++) {
#pragma unroll
          for (int s01 = 0; s01 < 2; s01++) {
            int base = 8 * s01;
            unsigned int wlo0, wlo1, whi0, whi1;
            if (t2 == 0) {
              wlo0 = cvt_pk_bf16(sA[base + 0], sA[base + 1]);
              wlo1 = cvt_pk_bf16(sA[base + 2], sA[base + 3]);
              whi0 = cvt_pk_bf16(sA[base + 4], sA[base + 5]);
              whi1 = cvt_pk_bf16(sA[base + 6], sA[base + 7]);
            } else {
              wlo0 = cvt_pk_bf16(sB[base + 0], sB[base + 1]);
              wlo1 = cvt_pk_bf16(sB[base + 2], sB[base + 3]);
              whi0 = cvt_pk_bf16(sB[base + 4], sB[base + 5]);
              whi1 = cvt_pk_bf16(sB[base + 6], sB[base + 7]);
            }
            asm volatile("v_permlane32_swap_b32 %0, %1" : "+v"(wlo0), "+v"(whi0));
            asm volatile("v_permlane32_swap_b32 %0, %1" : "+v"(wlo1), "+v"(whi1));
            union { unsigned int u[4]; bf16x8 v; } cc;
            cc.u[0] = wlo0; cc.u[1] = wlo1; cc.u[2] = whi0; cc.u[3] = whi1;
            pf[t2 * 2 + s01] = cc.v;
          }
        }
        __builtin_amdgcn_s_setprio(1);
#pragma unroll
        for (int db = 0; db < 2; db++) {
          const int row = db * 32 + q32;
#pragma unroll
          for (int ks = 0; ks < 4; ks++) {
            bf16x8 vf = *(const bf16x8*)(Vbase + row * 128 +
                                         (((ks * 2 + hi) ^ swz) * 16));
            accT[db] = __builtin_amdgcn_mfma_f32_32x32x16_bf16(vf, pf[ks],
                                                               accT[db], 0, 0, 0);
          }
        }
        __builtin_amdgcn_s_setprio(0);
      }
      asm volatile("s_waitcnt vmcnt(0) lgkmcnt(0)" ::: "memory");
      __builtin_amdgcn_s_barrier();
      __builtin_amdgcn_sched_barrier(0);
    }

    float* scrO = (float*)Kls;
    float* scrML = (float*)Vls;
    if (p == 1) {
#pragma unroll
      for (int db = 0; db < 2; db++)
#pragma unroll
        for (int r = 0; r < 16; r++)
          scrO[qsub * 2048 + (db * 16 + r) * 64 + lane] = accT[db][r];
      scrML[qsub * 64 + lane] = m_run;
      scrML[256 + qsub * 64 + lane] = l_run;
    }
    __syncthreads();
    if (p == 0) {
      float m_o = scrML[qsub * 64 + lane];
      float l_o = scrML[256 + qsub * 64 + lane];
      float mm = fmaxf(m_run, m_o);
      float ce = exp2f(m_run - mm), co = exp2f(m_o - mm);
      float lt = l_run * ce + l_o * co;
      float rinv = 1.f / lt;
      short* cp = Cb + (size_t)(b * TT + q0w + q32) * CDIM + h * 64;
#pragma unroll
      for (int db = 0; db < 2; db++)
#pragma unroll
        for (int rg = 0; rg < 4; rg++) {
          short4v pk4;
#pragma unroll
          for (int rr = 0; rr < 4; rr++) {
            int r = rg * 4 + rr;
            float v = accT[db][r] * ce +
                      scrO[qsub * 2048 + (db * 16 + r) * 64 + lane] * co;
            pk4[rr] = f2bf(v * rinv);
          }
          *(short4v*)(cp + db * 32 + rg * 8 + hi * 4) = pk4;
        }
    }
    __syncthreads();
  }
}

// ---------------------------------------------------------------------------
extern "C" void kernel_launch(void* const* d_in, const int* in_sizes, int n_in,
                              void* d_out, int out_size, void* d_ws, size_t ws_size,
                              hipStream_t stream) {
  const float* x       = (const float*)d_in[0];
  const float* W_attn  = (const float*)d_in[1];
  const float* b_attn  = (const float*)d_in[2];
  const float* A_attn  = (const float*)d_in[3];
  const float* B_attn  = (const float*)d_in[4];
  const float* W_proj  = (const float*)d_in[5];
  const float* b_proj  = (const float*)d_in[6];
  const float* A_proj  = (const float*)d_in[7];
  const float* B_proj  = (const float*)d_in[8];
  const float* kv_scale = (const float*)d_in[9];
  const float* kv_zp    = (const float*)d_in[10];
  float* out = (float*)d_out;

  char* p = (char*)d_ws;
  short* Xb    = (short*)p; p += (size_t)BT * CDIM * 2;
  short* Waug1 = (short*)p; p += (size_t)3072 * CDIM * 2;
  short* Waug2 = (short*)p; p += (size_t)1024 * CDIM * 2;
  short* Cb    = (short*)p; p += (size_t)BT * CDIM * 2;
  short* Qb    = (short*)p; p += (size_t)32 * TT * 64 * 2;
  short* Kb    = (short*)p; p += (size_t)32 * TT * 64 * 2;
  short* Vt    = (short*)p; p += (size_t)32 * TT * 64 * 2;

  packx_kernel<<<dim3(2048), dim3(256), 0, stream>>>(x, Xb);
  packw_eff_kernel<<<dim3(1536), dim3(256), 0, stream>>>(
      W_attn, B_attn, A_attn, Waug1);
  packw_eff_kernel<<<dim3(512), dim3(256), 0, stream>>>(
      W_proj, B_proj, A_proj, Waug2);
  gemm_qkv_kernel<<<dim3(768), dim3(256), 0, stream>>>(
      Xb, Waug1, b_attn, kv_scale, kv_zp, Qb, Kb, Vt);
  attn_kernel<<<dim3(256), dim3(512), 0, stream>>>(Qb, Kb, Vt, Cb);
  gemm_proj_kernel<<<dim3(256), dim3(256), 0, stream>>>(
      Cb, Waug2, b_proj, out);
}